// Round 3
// baseline (231.766 us; speedup 1.0000x reference)
//
#include <hip/hip_runtime.h>
#include <hip/hip_cooperative_groups.h>
#include <math.h>

namespace cg = cooperative_groups;

#define N_PER_B   262144
#define BATCH     8
#define NFEAT     14
#define TPB       256
#define BLOCKS    1024
#define BPB       (BLOCKS / BATCH)        // 128 blocks per batch
#define TPBATCH   (BPB * TPB)             // 32768 threads per batch
#define PAIRS     (N_PER_B / 2)           // 131072 record-pairs per batch
#define PPT       (PAIRS / TPBATCH)       // 4 pairs per thread

// ---- agent-scope (device) coherent f64 load/store: safe across XCD L2s ----
__device__ inline void st_agent(double* p, double v) {
    __hip_atomic_store((unsigned long long*)p, (unsigned long long)__double_as_longlong(v),
                       __ATOMIC_RELAXED, __HIP_MEMORY_SCOPE_AGENT);
}
__device__ inline double ld_agent(const double* p) {
    unsigned long long u = __hip_atomic_load((unsigned long long*)p,
                       __ATOMIC_RELAXED, __HIP_MEMORY_SCOPE_AGENT);
    return __longlong_as_double((long long)u);
}

// ---- per-quaternion math (fp32, identical to validated version) ----
__device__ inline void quat_accum(float w, float x, float y, float z, double* s) {
    w = fminf(fmaxf(w, -1000.0f), 1000.0f);
    x = fminf(fmaxf(x, -1000.0f), 1000.0f);
    y = fminf(fmaxf(y, -1000.0f), 1000.0f);
    z = fminf(fmaxf(z, -1000.0f), 1000.0f);
    float nrm = sqrtf(w * w + x * x + y * y + z * z);
    nrm = fmaxf(nrm, 1e-8f);
    float inv = 1.0f / nrm;
    w *= inv; x *= inv; y *= inv; z *= inv;
    float r0 = 2.0f * (x * z + w * y);
    float r1 = 2.0f * (y * z - w * x);
    float r2 = 1.0f - 2.0f * (x * x + y * y);
    s[0] += (double)r0 * (double)r0;
    s[1] += (double)r1 * (double)r1;
    s[2] += (double)r2 * (double)r2;
    s[3] += (double)r0 * (double)r1;
    s[4] += (double)r0 * (double)r2;
    s[5] += (double)r1 * (double)r2;
}

// ---- per-block accumulation -> partials[blockIdx.x][6] ----
__device__ inline void block_accum(const float* __restrict__ g,
                                   double* __restrict__ partials) {
    const int b     = blockIdx.x / BPB;
    const int xb    = blockIdx.x % BPB;
    const int tid_b = xb * TPB + threadIdx.x;
    const float4* __restrict__ gb4 =
        (const float4*)(g + (size_t)b * N_PER_B * NFEAT);

    double s[6] = {0, 0, 0, 0, 0, 0};

    // Record pair = 28 floats = 7 float4. q of rec0 = f4[1].w, f4[2].xyz;
    // q of rec1 = f4[5].yzw, f4[6].x. 2 float4 loads per record, independent.
    #pragma unroll
    for (int k = 0; k < PPT; ++k) {
        const size_t f4 = (size_t)7 * (size_t)(tid_b + k * TPBATCH);
        float4 a  = gb4[f4 + 1];
        float4 b2 = gb4[f4 + 2];
        float4 c  = gb4[f4 + 5];
        float4 d  = gb4[f4 + 6];
        quat_accum(a.w,  b2.x, b2.y, b2.z, s);
        quat_accum(c.y,  c.z,  c.w,  d.x,  s);
    }

    // 64-lane wave reduction
    #pragma unroll
    for (int off = 32; off > 0; off >>= 1) {
        #pragma unroll
        for (int k = 0; k < 6; ++k) s[k] += __shfl_down(s[k], off);
    }

    __shared__ double lds[TPB / 64][6];
    const int wave = threadIdx.x >> 6;
    const int lane = threadIdx.x & 63;
    if (lane == 0) {
        #pragma unroll
        for (int k = 0; k < 6; ++k) lds[wave][k] = s[k];
    }
    __syncthreads();
    if (threadIdx.x == 0) {
        #pragma unroll
        for (int k = 0; k < 6; ++k) {
            double v = lds[0][k] + lds[1][k] + lds[2][k] + lds[3][k];
            st_agent(&partials[(size_t)blockIdx.x * 6 + k], v);
        }
    }
}

// ---- closed-form 3x3 symmetric eigenvalues -> per-batch loss (fp64) ----
__device__ inline double batch_loss(const double* sraw) {
    const double invN = 1.0 / (double)N_PER_B;
    double a00 = sraw[0] * invN, a11 = sraw[1] * invN, a22 = sraw[2] * invN;
    double a01 = sraw[3] * invN, a02 = sraw[4] * invN, a12 = sraw[5] * invN;

    a00 = fmin(fmax(a00, -1e6), 1e6);
    a11 = fmin(fmax(a11, -1e6), 1e6);
    a22 = fmin(fmax(a22, -1e6), 1e6);
    a01 = fmin(fmax(a01, -1e6), 1e6);
    a02 = fmin(fmax(a02, -1e6), 1e6);
    a12 = fmin(fmax(a12, -1e6), 1e6);

    double q  = (a00 + a11 + a22) / 3.0;
    double p1 = a01 * a01 + a02 * a02 + a12 * a12;
    double d0 = a00 - q, d1 = a11 - q, d2 = a22 - q;
    double p2 = d0 * d0 + d1 * d1 + d2 * d2 + 2.0 * p1;

    double eigmax, eigmin;
    if (p2 <= 0.0) {
        eigmax = q;
        eigmin = q;
    } else {
        double p = sqrt(p2 / 6.0);
        double invp = 1.0 / p;
        double b00 = d0 * invp, b11 = d1 * invp, b22 = d2 * invp;
        double b01 = a01 * invp, b02 = a02 * invp, b12 = a12 * invp;
        double detB = b00 * (b11 * b22 - b12 * b12)
                    - b01 * (b01 * b22 - b12 * b02)
                    + b02 * (b01 * b12 - b11 * b02);
        double r = 0.5 * detB;
        r = fmin(1.0, fmax(-1.0, r));
        double phi = acos(r) / 3.0;
        eigmax = q + 2.0 * p * cos(phi);
        eigmin = q + 2.0 * p * cos(phi + 2.0 * M_PI / 3.0);
    }

    double max_safe = fmax(eigmax, 1e-6);
    double min_safe = fmax(eigmin, 1e-6);
    double ratio = max_safe / min_safe;
    ratio = fmin(fmax(ratio, 1.0), 1e6);
    return -log(ratio);
}

// ---- final reduction + eigen + mean, run by one 256-thread block ----
__device__ inline void final_block(const double* __restrict__ partials,
                                   float* __restrict__ out) {
    // 32 threads per batch; each loads 4 partials (BPB=128 = 32*4)
    const int bb = threadIdx.x >> 5;
    const int l  = threadIdx.x & 31;
    double t[6] = {0, 0, 0, 0, 0, 0};
    #pragma unroll
    for (int j = 0; j < BPB / 32; ++j) {
        const double* pp = partials + (size_t)(bb * BPB + l + 32 * j) * 6;
        #pragma unroll
        for (int k = 0; k < 6; ++k) t[k] += ld_agent(pp + k);
    }
    #pragma unroll
    for (int off = 16; off > 0; off >>= 1) {
        #pragma unroll
        for (int k = 0; k < 6; ++k) t[k] += __shfl_down(t[k], off, 32);
    }

    __shared__ double Tsum[BATCH][6];
    if (l == 0) {
        #pragma unroll
        for (int k = 0; k < 6; ++k) Tsum[bb][k] = t[k];
    }
    __syncthreads();

    __shared__ double losses[BATCH];
    if (threadIdx.x < BATCH) losses[threadIdx.x] = batch_loss(Tsum[threadIdx.x]);
    __syncthreads();

    if (threadIdx.x == 0) {
        double ssum = 0.0;
        #pragma unroll
        for (int i = 0; i < BATCH; ++i) ssum += losses[i];
        out[0] = (float)(ssum / (double)BATCH);
    }
}

// ---- single-node cooperative kernel ----
__global__ __launch_bounds__(TPB, 4) void fused_coop(const float* __restrict__ g,
                                                     float* __restrict__ out,
                                                     double* __restrict__ partials) {
    block_accum(g, partials);
    __threadfence();
    cg::this_grid().sync();
    if (blockIdx.x == 0) final_block(partials, out);
}

// ---- fallback: two plain nodes (kernel-boundary coherence) ----
__global__ __launch_bounds__(TPB, 4) void accum_part(const float* __restrict__ g,
                                                     double* __restrict__ partials) {
    block_accum(g, partials);
}
__global__ void finalize_part(const double* __restrict__ partials,
                              float* __restrict__ out) {
    final_block(partials, out);
}

extern "C" void kernel_launch(void* const* d_in, const int* in_sizes, int n_in,
                              void* d_out, int out_size, void* d_ws, size_t ws_size,
                              hipStream_t stream) {
    const float* g = (const float*)d_in[0];
    float* out = (float*)d_out;
    double* partials = (double*)d_ws;  // BLOCKS*6 doubles = 48 KB, fully
                                       // overwritten every call (poison-safe)

    void* args[3] = { (void*)&g, (void*)&out, (void*)&partials };
    hipError_t err = hipLaunchCooperativeKernel((const void*)fused_coop,
                                                dim3(BLOCKS), dim3(TPB),
                                                args, 0, stream);
    if (err != hipSuccess) {
        // deterministic fallback: identical math, two graph nodes
        accum_part<<<dim3(BLOCKS), dim3(TPB), 0, stream>>>(g, partials);
        finalize_part<<<1, dim3(TPB), 0, stream>>>(partials, out);
    }
}

// Round 4
// 28.405 us; speedup vs baseline: 8.1594x; 8.1594x over previous
//
#include <hip/hip_runtime.h>
#include <math.h>

#define N_PER_B   262144
#define BATCH     8
#define NFEAT     14
#define TPB       256
#define BPB       256                     // blocks per batch
#define BLOCKS    (BPB * BATCH)           // 2048 total
#define TPBATCH   (BPB * TPB)             // 65536 threads per batch
#define PAIRS     (N_PER_B / 2)           // 131072 record-pairs per batch
#define PPT       (PAIRS / TPBATCH)       // 2 pairs per thread

// ---- per-quaternion math (fp32, identical to validated rounds 1-3) ----
__device__ inline void quat_accum(float w, float x, float y, float z, double* s) {
    w = fminf(fmaxf(w, -1000.0f), 1000.0f);
    x = fminf(fmaxf(x, -1000.0f), 1000.0f);
    y = fminf(fmaxf(y, -1000.0f), 1000.0f);
    z = fminf(fmaxf(z, -1000.0f), 1000.0f);
    float nrm = sqrtf(w * w + x * x + y * y + z * z);
    nrm = fmaxf(nrm, 1e-8f);
    float inv = 1.0f / nrm;
    w *= inv; x *= inv; y *= inv; z *= inv;
    float r0 = 2.0f * (x * z + w * y);
    float r1 = 2.0f * (y * z - w * x);
    float r2 = 1.0f - 2.0f * (x * x + y * y);
    s[0] += (double)r0 * (double)r0;
    s[1] += (double)r1 * (double)r1;
    s[2] += (double)r2 * (double)r2;
    s[3] += (double)r0 * (double)r1;
    s[4] += (double)r0 * (double)r2;
    s[5] += (double)r1 * (double)r2;
}

// ---- kernel A: streaming accumulate -> partials[block][6] (plain stores) ----
__global__ __launch_bounds__(TPB) void accum_kernel(const float* __restrict__ g,
                                                    double* __restrict__ partials) {
    const int b     = blockIdx.y;
    const int tid_b = blockIdx.x * TPB + threadIdx.x;
    const float4* __restrict__ gb4 =
        (const float4*)(g + (size_t)b * N_PER_B * NFEAT);

    double s[6] = {0, 0, 0, 0, 0, 0};

    // Record pair = 28 floats = 7 float4. quat of rec0 = f4[1].w, f4[2].xyz;
    // quat of rec1 = f4[5].yzw, f4[6].x. Only 64B of each 112B pair is
    // fetched (32B-sector sparse: measured FETCH = 4/7 of input in round 3).
    #pragma unroll
    for (int k = 0; k < PPT; ++k) {
        const size_t f4 = (size_t)7 * (size_t)(tid_b + k * TPBATCH);
        float4 a  = gb4[f4 + 1];
        float4 b2 = gb4[f4 + 2];
        float4 c  = gb4[f4 + 5];
        float4 d  = gb4[f4 + 6];
        quat_accum(a.w, b2.x, b2.y, b2.z, s);
        quat_accum(c.y, c.z,  c.w,  d.x,  s);
    }

    // 64-lane wave reduction
    #pragma unroll
    for (int off = 32; off > 0; off >>= 1) {
        #pragma unroll
        for (int k = 0; k < 6; ++k) s[k] += __shfl_down(s[k], off);
    }

    __shared__ double lds[TPB / 64][6];
    const int wave = threadIdx.x >> 6;
    const int lane = threadIdx.x & 63;
    if (lane == 0) {
        #pragma unroll
        for (int k = 0; k < 6; ++k) lds[wave][k] = s[k];
    }
    __syncthreads();
    if (threadIdx.x == 0) {
        double* p = partials + (size_t)(b * BPB + blockIdx.x) * 6;
        #pragma unroll
        for (int k = 0; k < 6; ++k)
            p[k] = lds[0][k] + lds[1][k] + lds[2][k] + lds[3][k];
    }
}

// ---- closed-form 3x3 symmetric eigenvalues -> per-batch loss (fp64) ----
__device__ inline double batch_loss(const double* sraw) {
    const double invN = 1.0 / (double)N_PER_B;
    double a00 = sraw[0] * invN, a11 = sraw[1] * invN, a22 = sraw[2] * invN;
    double a01 = sraw[3] * invN, a02 = sraw[4] * invN, a12 = sraw[5] * invN;

    a00 = fmin(fmax(a00, -1e6), 1e6);
    a11 = fmin(fmax(a11, -1e6), 1e6);
    a22 = fmin(fmax(a22, -1e6), 1e6);
    a01 = fmin(fmax(a01, -1e6), 1e6);
    a02 = fmin(fmax(a02, -1e6), 1e6);
    a12 = fmin(fmax(a12, -1e6), 1e6);

    double q  = (a00 + a11 + a22) / 3.0;
    double p1 = a01 * a01 + a02 * a02 + a12 * a12;
    double d0 = a00 - q, d1 = a11 - q, d2 = a22 - q;
    double p2 = d0 * d0 + d1 * d1 + d2 * d2 + 2.0 * p1;

    double eigmax, eigmin;
    if (p2 <= 0.0) {
        eigmax = q;
        eigmin = q;
    } else {
        double p = sqrt(p2 / 6.0);
        double invp = 1.0 / p;
        double b00 = d0 * invp, b11 = d1 * invp, b22 = d2 * invp;
        double b01 = a01 * invp, b02 = a02 * invp, b12 = a12 * invp;
        double detB = b00 * (b11 * b22 - b12 * b12)
                    - b01 * (b01 * b22 - b12 * b02)
                    + b02 * (b01 * b12 - b11 * b02);
        double r = 0.5 * detB;
        r = fmin(1.0, fmax(-1.0, r));
        double phi = acos(r) / 3.0;
        eigmax = q + 2.0 * p * cos(phi);
        eigmin = q + 2.0 * p * cos(phi + 2.0 * M_PI / 3.0);
    }

    double max_safe = fmax(eigmax, 1e-6);
    double min_safe = fmax(eigmin, 1e-6);
    double ratio = max_safe / min_safe;
    ratio = fmin(fmax(ratio, 1.0), 1e6);
    return -log(ratio);
}

// ---- kernel B: reduce 2048x6 partials + eigen + mean (one block) ----
__global__ void finalize_kernel(const double* __restrict__ partials,
                                float* __restrict__ out) {
    // 32 lanes per batch (8 batches x 32 = 256 threads); each lane sums 8
    const int bb = threadIdx.x >> 5;
    const int l  = threadIdx.x & 31;
    double t[6] = {0, 0, 0, 0, 0, 0};
    #pragma unroll
    for (int j = 0; j < BPB / 32; ++j) {
        const double* pp = partials + (size_t)(bb * BPB + l + 32 * j) * 6;
        #pragma unroll
        for (int k = 0; k < 6; ++k) t[k] += pp[k];
    }
    #pragma unroll
    for (int off = 16; off > 0; off >>= 1) {
        #pragma unroll
        for (int k = 0; k < 6; ++k) t[k] += __shfl_down(t[k], off, 32);
    }

    __shared__ double Tsum[BATCH][6];
    if (l == 0) {
        #pragma unroll
        for (int k = 0; k < 6; ++k) Tsum[bb][k] = t[k];
    }
    __syncthreads();

    __shared__ double losses[BATCH];
    if (threadIdx.x < BATCH) losses[threadIdx.x] = batch_loss(Tsum[threadIdx.x]);
    __syncthreads();

    if (threadIdx.x == 0) {
        double ssum = 0.0;
        #pragma unroll
        for (int i = 0; i < BATCH; ++i) ssum += losses[i];
        out[0] = (float)(ssum / (double)BATCH);
    }
}

extern "C" void kernel_launch(void* const* d_in, const int* in_sizes, int n_in,
                              void* d_out, int out_size, void* d_ws, size_t ws_size,
                              hipStream_t stream) {
    const float* g = (const float*)d_in[0];
    float* out = (float*)d_out;
    double* partials = (double*)d_ws;  // BLOCKS*6 doubles = 96 KB, fully
                                       // overwritten every call (poison-safe)

    accum_kernel<<<dim3(BPB, BATCH), TPB, 0, stream>>>(g, partials);
    finalize_kernel<<<1, TPB, 0, stream>>>(partials, out);
}